// Round 24
// baseline (44.361 us; speedup 1.0000x reference)
//
#include <hip/hip_runtime.h>

#define DIM     400
#define NENT    14541
#define B       32
#define NCAND   14505
#define ABLK    228       // ceil(NENT/64) score blocks
#define NSC     1814      // scatter chunk
#define THREADS 256

typedef __attribute__((ext_vector_type(2))) _Float16 half2_t;

static __device__ __forceinline__ half2_t bch(unsigned u) {
    return __builtin_bit_cast(half2_t, u);
}
static __device__ __forceinline__ half2_t habs2(half2_t x) {
    unsigned u = __builtin_bit_cast(unsigned, x) & 0x7fff7fffu;
    return __builtin_bit_cast(half2_t, u);
}
static __device__ __forceinline__ unsigned pkh(float x, float y) {
    half2_t h;
    h.x = (_Float16)x;
    h.y = (_Float16)y;
    return __builtin_bit_cast(unsigned, h);
}
static __device__ __forceinline__ float dot2acc(half2_t m, float s) {
#if __has_builtin(__builtin_amdgcn_fdot2)
    const half2_t ones = {(_Float16)1.f, (_Float16)1.f};
    return __builtin_amdgcn_fdot2(m, ones, s, false);
#else
    return s + (float)m.x + (float)m.y;
#endif
}

// ---- phase A: entity-major, NO gather anywhere ----
// stab[e*32+b] = 0.98*sum(max(|c-q|,o)) + 0.02*sum(|c-q|)  (f16 inner math)
// Block = 64 sequential entities, 8 waves; wave = 8 ents (4 pairs x c2) x 32 batches.
// Prologue builds transposed f16 q/o LDS tables [j][b] (51.2 KB, R22-proven).
// Candidate rows: raw f32 ent stream, broadcast across 32 b-lanes, packed on the fly;
// 4 independent row streams/lane -> 8-16 loads in flight. Store = 128B/half-wave.
__global__ __launch_bounds__(512, 2)
void score_ent(const float* __restrict__ ent,
               const float* __restrict__ relc,
               const float* __restrict__ relo,
               const int*   __restrict__ pairs,
               float* __restrict__ stab) {
    __shared__ uint4 qs[1600];           // [j][b], j=0..49 (8 dims each), b=0..31
    __shared__ uint4 os[1600];           // pre-scaled 0.98*o
    const int tid = threadIdx.x;

    for (int i = tid; i < 1600; i += 512) {
        const int j = i >> 5;
        const int b = i & 31;
        const int h = pairs[2 * b + 0];
        const int r = pairs[2 * b + 1];
        const float4* hp = (const float4*)(ent  + (size_t)h * DIM) + 2 * j;
        const float4* cp = (const float4*)(relc + (size_t)r * DIM) + 2 * j;
        const float4* op = (const float4*)(relo + (size_t)r * DIM) + 2 * j;
        float4 h0 = hp[0], h1 = hp[1];
        float4 c0 = cp[0], c1 = cp[1];
        float4 v0 = op[0], v1 = op[1];
        uint4 qv, ov;
        qv.x = pkh(h0.x + c0.x, h0.y + c0.y);
        qv.y = pkh(h0.z + c0.z, h0.w + c0.w);
        qv.z = pkh(h1.x + c1.x, h1.y + c1.y);
        qv.w = pkh(h1.z + c1.z, h1.w + c1.w);
        ov.x = pkh(0.98f * v0.x, 0.98f * v0.y);
        ov.y = pkh(0.98f * v0.z, 0.98f * v0.w);
        ov.z = pkh(0.98f * v1.x, 0.98f * v1.y);
        ov.w = pkh(0.98f * v1.z, 0.98f * v1.w);
        qs[i] = qv;
        os[i] = ov;
    }
    __syncthreads();

    const int wid  = tid >> 6;
    const int lane = tid & 63;
    const int b    = lane & 31;
    const int c2   = lane >> 5;
    const int eBase = blockIdx.x * 64 + wid * 8;

    const int e0 = eBase + 0 + c2, e1 = eBase + 2 + c2;
    const int e2 = eBase + 4 + c2, e3 = eBase + 6 + c2;
    const float4* r0 = (const float4*)(ent + (size_t)(e0 < NENT ? e0 : NENT - 1) * DIM);
    const float4* r1 = (const float4*)(ent + (size_t)(e1 < NENT ? e1 : NENT - 1) * DIM);
    const float4* r2 = (const float4*)(ent + (size_t)(e2 < NENT ? e2 : NENT - 1) * DIM);
    const float4* r3 = (const float4*)(ent + (size_t)(e3 < NENT ? e3 : NENT - 1) * DIM);

    const half2_t K002 = {(_Float16)0.02f, (_Float16)0.02f};

#define PAIRE(cu, qu, ou, SS)                                   \
    {                                                           \
        half2_t cc_ = bch(cu), qq_ = bch(qu), oo_ = bch(ou);    \
        half2_t dd_ = cc_ - qq_;                                \
        half2_t aa_ = habs2(dd_);                               \
        half2_t ee_ = aa_ * K002 + oo_;                         \
        half2_t mm_ = __builtin_elementwise_max(aa_, ee_);      \
        SS = dot2acc(mm_, SS);                                  \
    }
#define PROCP(RP, SA, SB)                                       \
    {                                                           \
        float4 f0 = RP[2 * j], f1 = RP[2 * j + 1];              \
        uint4 ca;                                               \
        ca.x = pkh(f0.x, f0.y); ca.y = pkh(f0.z, f0.w);         \
        ca.z = pkh(f1.x, f1.y); ca.w = pkh(f1.z, f1.w);         \
        PAIRE(ca.x, qj.x, oj.x, SA) PAIRE(ca.y, qj.y, oj.y, SB) \
        PAIRE(ca.z, qj.z, oj.z, SA) PAIRE(ca.w, qj.w, oj.w, SB) \
    }

    float s00 = 0.f, s01 = 0.f, s10 = 0.f, s11 = 0.f;
    float s20 = 0.f, s21 = 0.f, s30 = 0.f, s31 = 0.f;

#pragma unroll 2
    for (int j = 0; j < 50; ++j) {
        const uint4 qj = qs[(j << 5) | b];
        const uint4 oj = os[(j << 5) | b];
        PROCP(r0, s00, s01)
        PROCP(r1, s10, s11)
        PROCP(r2, s20, s21)
        PROCP(r3, s30, s31)
    }
#undef PROCP
#undef PAIRE

    if (e0 < NENT) stab[(size_t)e0 * 32 + b] = s00 + s01;   // 128B per half-wave
    if (e1 < NENT) stab[(size_t)e1 * 32 + b] = s10 + s11;
    if (e2 < NENT) stab[(size_t)e2 * 32 + b] = s20 + s21;
    if (e3 < NENT) stab[(size_t)e3 * 32 + b] = s30 + s31;
}

// ---- phase B: out[b][n] = base[b] - stab[cidx[n]*32+b]; stab is 1.86MB L2-hot ----
__global__ __launch_bounds__(THREADS)
void scatter_k(const float* __restrict__ stab,
               const float* __restrict__ relo,
               const float* __restrict__ onev,
               const int*   __restrict__ pairs,
               const int*   __restrict__ cidx,
               float* __restrict__ out) {
    const int blk = blockIdx.x;
    const int b   = blk >> 3;
    const int ch  = blk & 7;
    const int tid = threadIdx.x;

    const int rl = pairs[2 * b + 1];
    float so = 0.f;
    if (tid < 100) {
        float4 v = ((const float4*)(relo + (size_t)rl * DIM))[tid];
        so = v.x + v.y + v.z + v.w;
    }
    for (int off = 32; off; off >>= 1) so += __shfl_down(so, off);
    __shared__ float red[4];
    if ((tid & 63) == 0) red[tid >> 6] = so;
    __syncthreads();
    const float base = onev[0] + 0.98f * (red[0] + red[1] + red[2] + red[3]);

    const int n0 = ch * NSC;
    const int n1 = (n0 + NSC < NCAND) ? n0 + NSC : NCAND;
    for (int n = n0 + tid; n < n1; n += THREADS) {
        const int ci = cidx[n];
        out[(size_t)b * NCAND + n] = base - stab[(size_t)ci * 32 + b];
    }
}

// ---- fallback (no ws): R9 f32 kernel verbatim ----
__global__ __launch_bounds__(THREADS, 2)
void score_f32(const float* __restrict__ ent,
               const float* __restrict__ relc,
               const float* __restrict__ relo,
               const float* __restrict__ onev,
               const int*   __restrict__ pairs,
               const int*   __restrict__ cidx,
               float* __restrict__ out) {
    const int fid  = blockIdx.x;
    const int xcd  = fid & 7;
    const int rest = fid >> 3;
    const int bq   = rest & 7;
    const int tc   = rest >> 3;
    const int t    = xcd + 8 * tc;

    const int tid  = threadIdx.x;
    const int lane = tid & 63;
    const int u    = lane & 15;
    const int g    = lane >> 4;
    const int b    = __builtin_amdgcn_readfirstlane(bq * 4 + (tid >> 6));

    const int hd = pairs[b * 2 + 0];
    const int rl = pairs[b * 2 + 1];
    const float4* hb = (const float4*)(ent  + (size_t)hd * DIM) + u;
    const float4* cb = (const float4*)(relc + (size_t)rl * DIM) + u;
    const float4* ob = (const float4*)(relo + (size_t)rl * DIM) + u;

    float4 q[7], o[7];
    float oa = 0.f;
#pragma unroll
    for (int k = 0; k < 6; ++k) {
        float4 h = hb[16 * k], c = cb[16 * k];
        q[k] = make_float4(h.x + c.x, h.y + c.y, h.z + c.z, h.w + c.w);
        o[k] = ob[16 * k];
        oa += o[k].x + o[k].y + o[k].z + o[k].w;
    }
    if (u < 4) {
        float4 h = hb[96], c = cb[96];
        q[6] = make_float4(h.x + c.x, h.y + c.y, h.z + c.z, h.w + c.w);
        o[6] = ob[96];
        oa += o[6].x + o[6].y + o[6].z + o[6].w;
    }
    oa += __shfl_xor(oa, 1);
    oa += __shfl_xor(oa, 2);
    oa += __shfl_xor(oa, 4);
    oa += __shfl_xor(oa, 8);
    const float base = onev[0] + 0.98f * oa;

    const float4* entu = (const float4*)ent + u;

#define E(vc, vq, vo, AM, AD)                     \
        {                                         \
            float d_ = (vc) - (vq);               \
            AM += fmaxf(fabsf(d_), (vo));         \
            AD += fabsf(d_);                      \
        }
#define F4(k, AM, AD)                             \
        E(cbuf[k].x, q[k].x, o[k].x, AM, AD)      \
        E(cbuf[k].y, q[k].y, o[k].y, AM, AD)      \
        E(cbuf[k].z, q[k].z, o[k].z, AM, AD)      \
        E(cbuf[k].w, q[k].w, o[k].w, AM, AD)

    for (int rr = t; rr < 3627; rr += 256) {
        const int cand = 4 * rr + g;
        const int ci   = cidx[cand < NCAND ? cand : NCAND - 1];
        const float4* p = entu + (size_t)ci * 100;

        float4 cbuf[7];
#pragma unroll
        for (int k = 0; k < 6; ++k) cbuf[k] = p[16 * k];
        if (u < 4) cbuf[6] = p[96];

        float am0 = 0.f, ad0 = 0.f, am1 = 0.f, ad1 = 0.f;
        F4(0, am0, ad0) F4(1, am1, ad1)
        F4(2, am0, ad0) F4(3, am1, ad1)
        F4(4, am0, ad0) F4(5, am1, ad1)
        if (u < 4) { F4(6, am0, ad0) }

        float s_ = fmaf(-0.98f, am0 + am1, -0.02f * (ad0 + ad1));
        s_ += __shfl_xor(s_, 1);
        s_ += __shfl_xor(s_, 2);
        s_ += __shfl_xor(s_, 4);
        s_ += __shfl_xor(s_, 8);

        if (u == 0 && cand < NCAND)
            out[(size_t)b * NCAND + cand] = base + s_;
    }
#undef F4
#undef E
}

extern "C" void kernel_launch(void* const* d_in, const int* in_sizes, int n_in,
                              void* d_out, int out_size, void* d_ws, size_t ws_size,
                              hipStream_t stream) {
    const float* ent   = (const float*)d_in[0];
    const float* relc  = (const float*)d_in[1];
    const float* relo  = (const float*)d_in[2];
    const float* onev  = (const float*)d_in[3];
    const int*   pairs = (const int*)d_in[4];
    const int*   cidx  = (const int*)d_in[5];
    float*       out   = (float*)d_out;

    const size_t need = (size_t)NENT * 32 * sizeof(float);   // 1.86 MB

    if (ws_size >= need) {
        float* stab = (float*)d_ws;
        score_ent<<<ABLK, 512, 0, stream>>>(ent, relc, relo, pairs, stab);
        scatter_k<<<B * 8, THREADS, 0, stream>>>(stab, relo, onev, pairs, cidx, out);
    } else {
        score_f32<<<8 * 8 * 32, THREADS, 0, stream>>>(
            ent, relc, relo, onev, pairs, cidx, out);
    }
}